// Round 22
// baseline (2795.206 us; speedup 1.0000x reference)
//
#include <hip/hip_runtime.h>
#include <hip/hip_bf16.h>

// HGT forward, MI355X — ROUND 22: bucketed CSR scatter (write-locality fix; was
// 225MB write-allocate -> ~payload). bidx aliases qq2_1 (dead until layer-0 proj4).
// Rest identical to r21: 8-deep scalarized gather2, multi-problem MFMA GEMMs.

#define HH 8
#define HID 128
#define INC 256
#define TTYPES 2
#define NBUK 512

typedef unsigned short u16;
typedef unsigned int u32;
typedef __attribute__((ext_vector_type(8))) short short8v;
typedef __attribute__((ext_vector_type(4))) float f32x4;

__device__ __forceinline__ float lo2f(u32 u) { return __uint_as_float(u << 16); }
__device__ __forceinline__ float hi2f(u32 u) { return __uint_as_float(u & 0xffff0000u); }
__device__ __forceinline__ u16 f2bf(float f) {
    u32 i = __float_as_uint(f);
    u32 r = i + 0x7fffu + ((i >> 16) & 1u);   // RNE
    return (u16)(r >> 16);
}
__device__ __forceinline__ float gelu_f(float x) {
    return 0.5f * x * (1.0f + erff(x * 0.7071067811865476f));
}

// ---------------- multi-problem MFMA GEMM: blockIdx.y picks pointer set -------------
template <typename TOUT> struct GA {
    const float* in[4]; const u16* w1[4]; const u16* w2[4];
    const float* b1[4]; const float* b2[4]; TOUT* out[4];
    const float* gate[4]; int ld[4];
};

template <int CIN, int COUT, int AIN, int AOUT, typename TOUT>
__global__ __launch_bounds__(256) void mgemmN_kernel(GA<TOUT> a, int nrows)
{
    __shared__ __align__(16) u16 Wt[128 * 136];
    const int y = blockIdx.y;
    const float* in = a.in[y];
    const u16* W1 = a.w1[y];
    const u16* W2 = a.w2[y];
    const float* b1 = a.b1[y];
    const float* b2 = a.b2[y];
    TOUT* out = a.out[y];
    const int ldout = a.ld[y];
    const bool split = (W2 != nullptr);

    const int tid = threadIdx.x;
    const int lane = tid & 63, wid = tid >> 6;
    const int rsub = lane & 15;
    const int kgrp = (lane >> 4) * 8;
    const int rowblk = blockIdx.x * 128;

    float g = 0.f;
    if (AOUT == 2) g = 1.0f / (1.0f + __expf(-a.gate[y][0]));

#pragma unroll
    for (int cc = 0; cc < COUT; cc += 128) {
        const u16* Ws = (split && cc) ? W2 : W1;
        const float* bs = (split && cc) ? b2 : b1;
        const int ldw  = split ? 128 : COUT;
        const int wcol = split ? 0 : cc;
        const int boff = split ? 0 : cc;

        f32x4 acc[2][8];
#pragma unroll
        for (int t2 = 0; t2 < 2; ++t2)
#pragma unroll
            for (int ct = 0; ct < 8; ++ct) acc[t2][ct] = (f32x4){0.f, 0.f, 0.f, 0.f};

#pragma unroll
        for (int kc = 0; kc < CIN; kc += 128) {
            __syncthreads();
            for (int i = tid; i < 128 * 32; i += 256) {
                int k = i >> 5, c4 = (i & 31) << 2;
                const uint2 w = *(const uint2*)&Ws[(size_t)(kc + k) * ldw + wcol + c4];
                Wt[(c4 + 0) * 136 + k] = (u16)(w.x & 0xffffu);
                Wt[(c4 + 1) * 136 + k] = (u16)(w.x >> 16);
                Wt[(c4 + 2) * 136 + k] = (u16)(w.y & 0xffffu);
                Wt[(c4 + 3) * 136 + k] = (u16)(w.y >> 16);
            }
            __syncthreads();
#pragma unroll
            for (int t2 = 0; t2 < 2; ++t2) {
                const int arow = rowblk + t2 * 64 + wid * 16 + rsub;
                const int asrc = (arow < nrows) ? arow : (nrows - 1);
                const float* ap0 = in + (size_t)asrc * CIN + kc;
#pragma unroll
                for (int ks = 0; ks < 4; ++ks) {
                    const int k0 = ks * 32 + kgrp;
                    const float4 a0 = *(const float4*)(ap0 + k0);
                    const float4 a1 = *(const float4*)(ap0 + k0 + 4);
                    float av[8] = {a0.x, a0.y, a0.z, a0.w, a1.x, a1.y, a1.z, a1.w};
                    short8v af;
#pragma unroll
                    for (int j = 0; j < 8; ++j) {
                        float xv = av[j];
                        if (AIN == 1) xv = gelu_f(xv);
                        af[j] = (short)f2bf(xv);
                    }
#pragma unroll
                    for (int ct = 0; ct < 8; ++ct) {
                        const short8v b =
                            *(const short8v*)&Wt[(ct * 16 + rsub) * 136 + k0];
                        acc[t2][ct] = __builtin_amdgcn_mfma_f32_16x16x32_bf16(
                            af, b, acc[t2][ct], 0, 0, 0);
                    }
                }
            }
        }
#pragma unroll
        for (int t2 = 0; t2 < 2; ++t2) {
            const int orow0 = rowblk + t2 * 64 + wid * 16 + (lane >> 4) * 4;
#pragma unroll
            for (int ct = 0; ct < 8; ++ct) {
                const int col = cc + ct * 16 + rsub;
                const float bv = bs[boff + ct * 16 + rsub];
#pragma unroll
                for (int r = 0; r < 4; ++r) {
                    const int orow = orow0 + r;
                    if (orow >= nrows) continue;
                    float v = acc[t2][ct][r] + bv;
                    if (AOUT == 1) v = fmaxf(v, 0.f);
                    size_t o = (size_t)orow * ldout + col;
                    if constexpr (sizeof(TOUT) == 2) {
                        ((u16*)out)[o] = f2bf(v);
                    } else {
                        float* of = (float*)out;
                        if (AOUT == 2) v = g * v + (1.0f - g) * of[o];
                        of[o] = v;
                    }
                }
            }
        }
    }
}

// ---------------- decoder GEMM (f32 W, direct A loads) ------------------------------
template <int CIN, int COUT, int AOUT>
__global__ __launch_bounds__(256) void dgemm_kernel(
    const float* __restrict__ in, const float* __restrict__ W,
    const float* __restrict__ bias, float* __restrict__ out, int nrows)
{
    __shared__ __align__(16) u16 Wt[128 * 136];
    const int tid = threadIdx.x;
    const int lane = tid & 63, wid = tid >> 6;
    const int rsub = lane & 15;
    const int kgrp = (lane >> 4) * 8;
    const int rowblk = blockIdx.x * 128;

#pragma unroll
    for (int cc = 0; cc < COUT; cc += 128) {
        f32x4 acc[2][8];
#pragma unroll
        for (int t2 = 0; t2 < 2; ++t2)
#pragma unroll
            for (int ct = 0; ct < 8; ++ct) acc[t2][ct] = (f32x4){0.f, 0.f, 0.f, 0.f};

#pragma unroll
        for (int kc = 0; kc < CIN; kc += 128) {
            __syncthreads();
            for (int i = tid; i < 128 * 32; i += 256) {
                int k = i >> 5, c4 = (i & 31) << 2;
                const float4 w = *(const float4*)&W[(size_t)(kc + k) * COUT + cc + c4];
                Wt[(c4 + 0) * 136 + k] = f2bf(w.x);
                Wt[(c4 + 1) * 136 + k] = f2bf(w.y);
                Wt[(c4 + 2) * 136 + k] = f2bf(w.z);
                Wt[(c4 + 3) * 136 + k] = f2bf(w.w);
            }
            __syncthreads();
#pragma unroll
            for (int t2 = 0; t2 < 2; ++t2) {
                const int arow = rowblk + t2 * 64 + wid * 16 + rsub;
                const int asrc = (arow < nrows) ? arow : (nrows - 1);
                const float* ap0 = in + (size_t)asrc * CIN + kc;
#pragma unroll
                for (int ks = 0; ks < 4; ++ks) {
                    const int k0 = ks * 32 + kgrp;
                    const float4 a0 = *(const float4*)(ap0 + k0);
                    const float4 a1 = *(const float4*)(ap0 + k0 + 4);
                    float av[8] = {a0.x, a0.y, a0.z, a0.w, a1.x, a1.y, a1.z, a1.w};
                    short8v af;
#pragma unroll
                    for (int j = 0; j < 8; ++j) af[j] = (short)f2bf(av[j]);
#pragma unroll
                    for (int ct = 0; ct < 8; ++ct) {
                        const short8v b =
                            *(const short8v*)&Wt[(ct * 16 + rsub) * 136 + k0];
                        acc[t2][ct] = __builtin_amdgcn_mfma_f32_16x16x32_bf16(
                            af, b, acc[t2][ct], 0, 0, 0);
                    }
                }
            }
        }
#pragma unroll
        for (int t2 = 0; t2 < 2; ++t2) {
            const int orow0 = rowblk + t2 * 64 + wid * 16 + (lane >> 4) * 4;
#pragma unroll
            for (int ct = 0; ct < 8; ++ct) {
                const int col = cc + ct * 16 + rsub;
                const float bv = bias[col];
#pragma unroll
                for (int r = 0; r < 4; ++r) {
                    const int orow = orow0 + r;
                    if (orow >= nrows) continue;
                    float v = acc[t2][ct][r] + bv;
                    if (AOUT == 1) v = fmaxf(v, 0.f);
                    out[(size_t)orow * COUT + col] = v;
                }
            }
        }
    }
}

// ---------------- convert 4 weight arrays to bf16 pool ------------------------------
__global__ void cvt4_kernel(const float* s0, const float* s1, const float* s2,
                            const float* s3, u16* __restrict__ pool, int n) {
    int y = blockIdx.y;
    const float* s = y == 0 ? s0 : y == 1 ? s1 : y == 2 ? s2 : s3;
    int i = blockIdx.x * 256 + threadIdx.x;
    if (i < n) pool[(size_t)y * n + i] = f2bf(s[i]);
}

// --- fuse arel into qW for ALL (l, dt, half): qWA_all[l*2+dt] [128][256] bf16 -------
__global__ __launch_bounds__(256) void fuse_all_kernel(
    const float* __restrict__ qW, const float* __restrict__ qb,
    const float* __restrict__ arel, u16* __restrict__ qWA_all,
    float* __restrict__ qbA_all)
{
    static const int etdt_[2][2] = {{1, 2}, {0, 3}};
    const int z = blockIdx.y;
    const int l = z >> 2, dt = (z >> 1) & 1, half = z & 1;
    const int et = etdt_[dt][half];
    const int rel = l * 4 + et, bd = l * 2 + dt;
    const float* qWl = qW + (size_t)bd * HID * HID;
    const float* qbl = qb + (size_t)bd * HID;
    const float* ar  = arel + (size_t)rel * 2048;
    u16* wout  = qWA_all + (size_t)bd * HID * 256;
    float* bout = qbA_all + (size_t)bd * 256;

    __shared__ float Al[2048];
    int tid = threadIdx.x;
    for (int i = tid; i < 2048; i += 256) Al[i] = ar[i];
    __syncthreads();
    int idx = blockIdx.x * 256 + tid;      // 64 x 256 = 16384
    int c = idx >> 7, col = idx & 127;
    int h = col >> 4, d = col & 15;
    const float* Ah = &Al[h * 256 + d * 16];
    const float* qr = &qWl[(size_t)c * 128 + h * 16];
    float acc = 0.f;
#pragma unroll
    for (int e = 0; e < 16; ++e) acc += qr[e] * Ah[e];
    wout[(size_t)c * 256 + half * 128 + col] = f2bf(acc);
    if (blockIdx.x == 0 && tid < 128) {
        int h2 = tid >> 4, d2 = tid & 15;
        const float* Ah2 = &Al[h2 * 256 + d2 * 16];
        const float* qb2 = &qbl[h2 * 16];
        float accb = 0.f;
#pragma unroll
        for (int e = 0; e < 16; ++e) accb += qb2[e] * Ah2[e];
        bout[half * 128 + tid] = accb;
    }
}

// ---------------- CSR-gather attention x2 edge types; 8-deep pipeline ---------------
__global__ __launch_bounds__(256) void gather2_kernel(
    const u32* __restrict__ qqA, const u32* __restrict__ qqB,
    const u32* __restrict__ kvA, const u32* __restrict__ kvB,
    const int* __restrict__ offA, const int* __restrict__ offB,
    const int* __restrict__ csrcA, const int* __restrict__ csrcB,
    const float* __restrict__ prelA, const float* __restrict__ prelB,
    const float* __restrict__ mrelA, const float* __restrict__ mrelB,
    float* __restrict__ aggA, float* __restrict__ aggB,
    int N, int accA, int accB)
{
    const int which = blockIdx.y;
    const u32* qq   = which ? qqB : qqA;
    const u32* kv   = which ? kvB : kvA;
    const int* off  = which ? offB : offA;
    const int* csrc = which ? csrcB : csrcA;
    const float* prel = which ? prelB : prelA;
    const float* mrel = which ? mrelB : mrelA;
    float* agg = which ? aggB : aggA;
    const int accum = which ? accB : accA;

    __shared__ float M[8 * 264];
    int tid = threadIdx.x;
    for (int i = tid; i < 2048; i += 256) M[(i >> 8) * 264 + (i & 255)] = mrel[i];
    __syncthreads();
    int lane = tid & 63, wid = tid >> 6;
    int h = lane >> 3, dp = lane & 7;
    int dst = blockIdx.x * 4 + wid;
    if (dst >= N) return;

    float prl = prel[h] * 0.25f;
    const u32 qu = qq[(size_t)dst * 128 + lane];
    const float qx = lo2f(qu), qy = hi2f(qu);
    const int beg = __builtin_amdgcn_readfirstlane(off[dst]);
    const int end = __builtin_amdgcn_readfirstlane(off[dst + 1]);
    float acc0 = 0.f, acc1 = 0.f, ssum = 0.f;

    u32 kA[4], vA[4], kB[4], vB[4];

    auto LOADG = [&](int g, u32* kk, u32* vv) {
#pragma unroll
        for (int i = 0; i < 4; ++i) {
            int e = g + i;
            int s = (e < end) ? csrc[e] : 0;
            const u32* base = kv + ((size_t)(u32)s << 7);
            kk[i] = base[lane];
            vv[i] = base[64 + lane];
        }
    };
    auto COMPG = [&](int g, const u32* kk, const u32* vv) {
#pragma unroll
        for (int i = 0; i < 4; ++i) {
            float p = qx * lo2f(kk[i]) + qy * hi2f(kk[i]);
            p += __shfl_xor(p, 1);
            p += __shfl_xor(p, 2);
            p += __shfl_xor(p, 4);
            float sarg = fminf(fmaxf(p * prl, -60.f), 60.f);
            float ex = (g + i < end) ? __expf(sarg) : 0.f;
            ssum += ex;
            acc0 += ex * lo2f(vv[i]);
            acc1 += ex * hi2f(vv[i]);
        }
    };

    if (beg < end) {
        LOADG(beg, kA, vA);
        LOADG(beg + 4, kB, vB);
        int g = beg;
        for (;;) {
            COMPG(g, kA, vA);
            if (g + 8 < end) LOADG(g + 8, kA, vA);
            g += 4;
            if (g >= end) break;
            COMPG(g, kB, vB);
            if (g + 8 < end) LOADG(g + 8, kB, vB);
            g += 4;
            if (g >= end) break;
        }
    }

    float inv = 1.0f / (ssum + 1e-16f);
    acc0 *= inv; acc1 *= inv;

    float o0 = 0.f, o1 = 0.f;
    const float* Mh = &M[h * 264];
#pragma unroll
    for (int dd = 0; dd < 8; ++dd) {
        float b0 = __shfl(acc0, (h << 3) | dd);
        float b1 = __shfl(acc1, (h << 3) | dd);
        const float2 m0 = *(const float2*)&Mh[(2 * dd) * 16 + dp * 2];
        const float2 m1 = *(const float2*)&Mh[(2 * dd + 1) * 16 + dp * 2];
        o0 += b0 * m0.x + b1 * m1.x;
        o1 += b0 * m0.y + b1 * m1.y;
    }
    float* ap = &agg[(size_t)dst * 128 + lane * 2];
    if (accum) { ap[0] += o0; ap[1] += o1; }
    else       { ap[0] = o0;  ap[1] = o1;  }
}

// ---------------- CSR build: bucketed two-phase scatter -----------------------------
__global__ void hist4_kernel(const int* e0, const int* e1, const int* e2,
                             const int* e3, int* __restrict__ deg, int E, int N) {
    int et = blockIdx.y;
    const int* ei = et == 0 ? e0 : et == 1 ? e1 : et == 2 ? e2 : e3;
    int i = blockIdx.x * 256 + threadIdx.x;
    if (i < E) atomicAdd(&deg[et * N + ei[E + i]], 1);
}
// bucket histogram: bucket = dst >> bshift (< NBUK)
__global__ void bhist4_kernel(const int* e0, const int* e1, const int* e2,
                              const int* e3, int* __restrict__ bcnt,
                              int E, int bshift) {
    int et = blockIdx.y;
    const int* ei = et == 0 ? e0 : et == 1 ? e1 : et == 2 ? e2 : e3;
    int i = blockIdx.x * 256 + threadIdx.x;
    if (i < E) atomicAdd(&bcnt[et * NBUK + (ei[E + i] >> bshift)], 1);
}
// exclusive scan of NBUK bucket counts per et; writes bboff and brun
__global__ __launch_bounds__(256) void bscan4_kernel(const int* __restrict__ bcnt,
                                                     int* __restrict__ bboff,
                                                     int* __restrict__ brun) {
    int et = blockIdx.x, tid = threadIdx.x;
    int a = bcnt[et * NBUK + 2 * tid], b = bcnt[et * NBUK + 2 * tid + 1];
    int s = a + b;
    __shared__ int sm[256];
    sm[tid] = s; __syncthreads();
    for (int d = 1; d < 256; d <<= 1) {
        int t = (tid >= d) ? sm[tid - d] : 0;
        __syncthreads();
        sm[tid] += t;
        __syncthreads();
    }
    int excl = sm[tid] - s;
    bboff[et * NBUK + 2 * tid] = excl;
    bboff[et * NBUK + 2 * tid + 1] = excl + a;
    brun[et * NBUK + 2 * tid] = excl;
    brun[et * NBUK + 2 * tid + 1] = excl + a;
}
// append edge index to its bucket segment (few hot lines per bucket)
__global__ void bscat4_kernel(const int* e0, const int* e1, const int* e2,
                              const int* e3, int* __restrict__ brun,
                              int* __restrict__ bidx, int E, int bshift) {
    int et = blockIdx.y;
    const int* ei = et == 0 ? e0 : et == 1 ? e1 : et == 2 ? e2 : e3;
    int i = blockIdx.x * 256 + threadIdx.x;
    if (i < E) {
        int b = ei[E + i] >> bshift;
        int pos = atomicAdd(&brun[et * NBUK + b], 1);
        bidx[(size_t)et * E + pos] = i;
    }
}
__global__ __launch_bounds__(256) void scan_part4(const int* __restrict__ deg,
                                                  int* __restrict__ bsum, int N) {
    int et = blockIdx.y, b = blockIdx.x, tid = threadIdx.x;
    deg += (size_t)et * N;
    int base = b * 1024 + tid * 4;
    int s = 0;
#pragma unroll
    for (int i = 0; i < 4; ++i) { int idx = base + i; if (idx < N) s += deg[idx]; }
    __shared__ int sm[256];
    sm[tid] = s; __syncthreads();
    for (int d = 128; d > 0; d >>= 1) {
        if (tid < d) sm[tid] += sm[tid + d];
        __syncthreads();
    }
    if (tid == 0) bsum[et * 64 + b] = sm[0];
}
__global__ __launch_bounds__(256) void scan_top4(int* __restrict__ bsum,
                                                 int* __restrict__ offs,
                                                 int NB, int N) {
    int et = blockIdx.x, tid = threadIdx.x;
    bsum += et * 64;
    int* off = offs + (size_t)et * (N + 1);
    __shared__ int sm[256];
    int v = (tid < NB) ? bsum[tid] : 0;
    sm[tid] = v; __syncthreads();
    for (int d = 1; d < 256; d <<= 1) {
        int t = (tid >= d) ? sm[tid - d] : 0;
        __syncthreads();
        sm[tid] += t;
        __syncthreads();
    }
    if (tid < NB) bsum[tid] = sm[tid] - v;
    if (tid == 255) off[N] = sm[255];
}
__global__ __launch_bounds__(256) void scan_fin4(const int* __restrict__ deg,
                                                 const int* __restrict__ bsum,
                                                 int* __restrict__ offs, int N) {
    int et = blockIdx.y, b = blockIdx.x, tid = threadIdx.x;
    deg += (size_t)et * N;
    bsum += et * 64;
    int* off = offs + (size_t)et * (N + 1);
    int base = b * 1024 + tid * 4;
    int v[4]; int s = 0;
#pragma unroll
    for (int i = 0; i < 4; ++i) {
        int idx = base + i;
        v[i] = (idx < N) ? deg[idx] : 0;
        s += v[i];
    }
    __shared__ int sm[256];
    sm[tid] = s; __syncthreads();
    for (int d = 1; d < 256; d <<= 1) {
        int t = (tid >= d) ? sm[tid - d] : 0;
        __syncthreads();
        sm[tid] += t;
        __syncthreads();
    }
    int run = bsum[b] + sm[tid] - s;
#pragma unroll
    for (int i = 0; i < 4; ++i) {
        int idx = base + i;
        if (idx < N) { off[idx] = run; run += v[i]; }
    }
}
// final scatter in bucket order: cnt/csrc writes land in per-bucket L2-hot windows
__global__ void scatter4b_kernel(const int* e0, const int* e1, const int* e2,
                                 const int* e3, const int* __restrict__ bidx,
                                 const int* __restrict__ offs, int* __restrict__ cnt,
                                 int* __restrict__ csrcs, int E, int N) {
    int et = blockIdx.y;
    const int* ei = et == 0 ? e0 : et == 1 ? e1 : et == 2 ? e2 : e3;
    int j = blockIdx.x * 256 + threadIdx.x;
    if (j < E) {
        int i = bidx[(size_t)et * E + j];
        int s = ei[i], d = ei[E + i];
        int pos = offs[(size_t)et * (N + 1) + d] + atomicAdd(&cnt[et * N + d], 1);
        csrcs[(size_t)et * E + pos] = s;
    }
}

// ---------------- L2 normalize: one wave per row, f32 -> f32 ------------------------
__global__ __launch_bounds__(256) void nnorm(
    const float* __restrict__ h0, float* __restrict__ emb, int N)
{
    int lane = threadIdx.x & 63, wid = threadIdx.x >> 6;
    int n = blockIdx.x * 4 + wid;
    if (n >= N) return;
    const float2 v = *(const float2*)&h0[(size_t)n * 128 + lane * 2];
    float s = v.x * v.x + v.y * v.y;
#pragma unroll
    for (int m = 1; m < 64; m <<= 1) s += __shfl_xor(s, m);
    float sc = 1.0f / fmaxf(sqrtf(s), 1e-12f);
    if (!isfinite(sc)) sc = 0.f;
    float2* op = (float2*)&emb[(size_t)n * 128 + lane * 2];
    *op = make_float2(v.x * sc, v.y * sc);
}

// ---------------- sentinel (f32) ----------------------------------------------------
__global__ void sentinel_kernel(float* out, int n, float val) {
    int i = blockIdx.x * 256 + threadIdx.x;
    if (i < n) out[i] = val;
}

extern "C" void kernel_launch(void* const* d_in, const int* in_sizes, int n_in,
                              void* d_out, int out_size, void* d_ws, size_t ws_size,
                              hipStream_t stream)
{
    const int N = in_sizes[0] / (TTYPES * INC);
    const int E = in_sizes[19] / 2;
    const size_t NH = (size_t)N * HID;

    const size_t need = 6 * NH * 4;   // 153.6 MB (proven available)
    if (ws_size < need) {
        sentinel_kernel<<<(out_size + 255) / 256, 256, 0, stream>>>(
            (float*)d_out, out_size, 30.0f);
        return;
    }

    const float* x     = (const float*)d_in[0];
    const float* encW  = (const float*)d_in[1];
    const float* encb  = (const float*)d_in[2];
    const float* kW    = (const float*)d_in[3];
    const float* kb_   = (const float*)d_in[4];
    const float* qW    = (const float*)d_in[5];
    const float* qb    = (const float*)d_in[6];
    const float* vW    = (const float*)d_in[7];
    const float* vb_   = (const float*)d_in[8];
    const float* aW    = (const float*)d_in[9];
    const float* ab    = (const float*)d_in[10];
    const float* skipw = (const float*)d_in[11];
    const float* arel  = (const float*)d_in[12];
    const float* mrel  = (const float*)d_in[13];
    const float* prel  = (const float*)d_in[14];
    const float* dW1   = (const float*)d_in[15];
    const float* db1   = (const float*)d_in[16];
    const float* dW2   = (const float*)d_in[17];
    const float* db2   = (const float*)d_in[18];

    float* hbuf = (float*)d_ws;
    float* agg0 = hbuf + 2 * NH;
    u32* kv0    = (u32*)(agg0 + NH);      // [N][128] k|v packed bf16, src type 0
    u32* kv1    = kv0 + NH;               // src type 1
    u32* qq2_0  = kv1 + NH;               // [N][128] qq halves, dt=0

    // ---- d_out scratch ----
    float* agg1 = (float*)d_out;                 // emb region, dead before nnorm
    int*   ip   = (int*)((float*)d_out + NH);    // rec region
    int* deg   = ip;  ip += 4 * N;
    int* cnt   = ip;  ip += 4 * N;
    int* bcnt  = ip;  ip += 4 * NBUK;            // contiguous with deg/cnt: one memset
    int* bboff = ip;  ip += 4 * NBUK;
    int* brun  = ip;  ip += 4 * NBUK;
    int* offs  = ip;  ip += 4 * (N + 1);
    int* csrcs = ip;  ip += 4 * E;
    u16* qWA_all = (u16*)ip;                     // [4][128][256] bf16
    float* qbA_all = (float*)(qWA_all + 4 * HID * 256);
    int* bsum   = (int*)(qbA_all + 4 * 256);     // [4][64]
    u16* wpool  = (u16*)(bsum + 256);            // 4 x 65536 bf16 weights
    const int WN = 65536;
    u16* encB = wpool;
    u16* kB   = wpool + WN;
    u16* vB   = wpool + 2 * WN;
    u16* aB   = wpool + 3 * WN;
    u32* qq2_1 = (u32*)(wpool + 4 * WN);         // [N][128] qq halves, dt=1
    int* bidx  = (int*)qq2_1;                    // ALIAS: dead until layer-0 proj4
    u32* qq2[2] = {qq2_0, qq2_1};
    float* aggs[2] = {agg0, agg1};

    const int egrid = (E + 255) / 256;
    const int RB    = (N + 127) / 128;
    const int GW    = (N + 3) / 4;
    const int NB1   = (N + 1023) >> 10;
    int bshift = 0;
    while (((N - 1) >> bshift) >= NBUK) ++bshift;

    const int* e0 = (const int*)d_in[19];
    const int* e1 = (const int*)d_in[20];
    const int* e2 = (const int*)d_in[21];
    const int* e3 = (const int*)d_in[22];

    // ---- prep: weight pool + all arel folds + CSR build (bucketed) ----
    cvt4_kernel<<<dim3(WN / 256, 4), 256, 0, stream>>>(encW, kW, vW, aW, wpool, WN);
    fuse_all_kernel<<<dim3(64, 8), 256, 0, stream>>>(qW, qb, arel, qWA_all, qbA_all);
    hipMemsetAsync(deg, 0, ((size_t)8 * N + 4 * NBUK) * 4, stream);  // deg+cnt+bcnt
    bhist4_kernel<<<dim3(egrid, 4), 256, 0, stream>>>(e0, e1, e2, e3, bcnt, E, bshift);
    bscan4_kernel<<<4, 256, 0, stream>>>(bcnt, bboff, brun);
    bscat4_kernel<<<dim3(egrid, 4), 256, 0, stream>>>(e0, e1, e2, e3, brun, bidx,
                                                      E, bshift);
    hist4_kernel<<<dim3(egrid, 4), 256, 0, stream>>>(e0, e1, e2, e3, deg, E, N);
    scan_part4<<<dim3(NB1, 4), 256, 0, stream>>>(deg, bsum, N);
    scan_top4<<<4, 256, 0, stream>>>(bsum, offs, NB1, N);
    scan_fin4<<<dim3(NB1, 4), 256, 0, stream>>>(deg, bsum, offs, N);
    scatter4b_kernel<<<dim3(egrid, 4), 256, 0, stream>>>(e0, e1, e2, e3, bidx, offs,
                                                         cnt, csrcs, E, N);

    // ---- encoder: both node types in one dispatch ----
    {
        GA<float> ga{};
        for (int t = 0; t < 2; ++t) {
            ga.in[t] = x + (size_t)t * N * INC;
            ga.w1[t] = encB + (size_t)t * INC * HID;
            ga.w2[t] = nullptr;
            ga.b1[t] = encb + t * HID;
            ga.out[t] = hbuf + t * NH;
            ga.ld[t] = HID;
        }
        mgemmN_kernel<INC, HID, 0, 1, float><<<dim3(RB, 2), 256, 0, stream>>>(ga, N);
    }

    for (int l = 0; l < 2; ++l) {
        // proj4: qq_dt0, qq_dt1, kv_st0, kv_st1 (all read pre-update h)
        {
            GA<u16> ga{};
            for (int dt = 0; dt < 2; ++dt) {
                int bd = l * 2 + dt;
                ga.in[dt] = hbuf + dt * NH;
                ga.w1[dt] = qWA_all + (size_t)bd * HID * 256;
                ga.w2[dt] = nullptr;
                ga.b1[dt] = qbA_all + (size_t)bd * 256;
                ga.out[dt] = (u16*)qq2[dt];
                ga.ld[dt] = 256;
            }
            u32* kvs[2] = {kv0, kv1};
            for (int st = 0; st < 2; ++st) {
                int bs = l * 2 + st, y = 2 + st;
                ga.in[y] = hbuf + st * NH;
                ga.w1[y] = kB + (size_t)bs * HID * HID;
                ga.w2[y] = vB + (size_t)bs * HID * HID;
                ga.b1[y] = kb_ + (size_t)bs * HID;
                ga.b2[y] = vb_ + (size_t)bs * HID;
                ga.out[y] = (u16*)kvs[st];
                ga.ld[y] = 256;
            }
            mgemmN_kernel<HID, 256, 0, 0, u16><<<dim3(RB, 4), 256, 0, stream>>>(ga, N);
        }
        gather2_kernel<<<dim3(GW, 2), 256, 0, stream>>>(
            qq2_1, qq2_0, kv0, kv1,
            offs + 0 * (N + 1), offs + 1 * (size_t)(N + 1),
            csrcs + 0 * (size_t)E, csrcs + 1 * (size_t)E,
            prel + (size_t)(l * 4 + 0) * HH, prel + (size_t)(l * 4 + 1) * HH,
            mrel + (size_t)(l * 4 + 0) * 2048, mrel + (size_t)(l * 4 + 1) * 2048,
            agg1, agg0, N, 0, 0);
        gather2_kernel<<<dim3(GW, 2), 256, 0, stream>>>(
            qq2_0 + 64, qq2_1 + 64, kv0, kv1,
            offs + 2 * (size_t)(N + 1), offs + 3 * (size_t)(N + 1),
            csrcs + 2 * (size_t)E, csrcs + 3 * (size_t)E,
            prel + (size_t)(l * 4 + 2) * HH, prel + (size_t)(l * 4 + 3) * HH,
            mrel + (size_t)(l * 4 + 2) * 2048, mrel + (size_t)(l * 4 + 3) * 2048,
            agg0, agg1, N, 1, 1);
        // a2: h[t] = g*(gelu(agg[t]) @ aW + ab) + (1-g)*h[t]
        {
            GA<float> ga{};
            for (int t = 0; t < 2; ++t) {
                int b = l * 2 + t;
                ga.in[t] = aggs[t];
                ga.w1[t] = aB + (size_t)b * HID * HID;
                ga.w2[t] = nullptr;
                ga.b1[t] = ab + (size_t)b * HID;
                ga.out[t] = hbuf + t * NH;
                ga.gate[t] = skipw + b;
                ga.ld[t] = HID;
            }
            mgemmN_kernel<HID, HID, 1, 2, float><<<dim3(RB, 2), 256, 0, stream>>>(ga, N);
        }
    }

    float* emb = (float*)d_out;           // [N][128] f32
    float* rec = emb + NH;                // [N][256] f32
    nnorm<<<GW, 256, 0, stream>>>(hbuf, emb, N);
    dgemm_kernel<HID, HID, 1><<<RB, 256, 0, stream>>>(hbuf, dW1, db1, agg0, N);
    dgemm_kernel<HID, 256, 0><<<RB, 256, 0, stream>>>(agg0, dW2, db2, rec, N);
}

// Round 23
// 1287.303 us; speedup vs baseline: 2.1714x; 2.1714x over previous
//
#include <hip/hip_runtime.h>
#include <hip/hip_bf16.h>

// HGT forward, MI355X — ROUND 23: REVERT to round-21 configuration (empirical best,
// 1290 µs). Round-22's bucketed scatter caused 512-address atomic serialization
// (870 µs/dispatch) — reverted. 8-deep scalarized gather2, multi-problem MFMA
// GEMMs, fuse_all hoisted, dual kv tables, merged CSR build, f32 outputs.

#define HH 8
#define HID 128
#define INC 256
#define TTYPES 2

typedef unsigned short u16;
typedef unsigned int u32;
typedef __attribute__((ext_vector_type(8))) short short8v;
typedef __attribute__((ext_vector_type(4))) float f32x4;

__device__ __forceinline__ float lo2f(u32 u) { return __uint_as_float(u << 16); }
__device__ __forceinline__ float hi2f(u32 u) { return __uint_as_float(u & 0xffff0000u); }
__device__ __forceinline__ u16 f2bf(float f) {
    u32 i = __float_as_uint(f);
    u32 r = i + 0x7fffu + ((i >> 16) & 1u);   // RNE
    return (u16)(r >> 16);
}
__device__ __forceinline__ float gelu_f(float x) {
    return 0.5f * x * (1.0f + erff(x * 0.7071067811865476f));
}

// ---------------- multi-problem MFMA GEMM: blockIdx.y picks pointer set -------------
template <typename TOUT> struct GA {
    const float* in[4]; const u16* w1[4]; const u16* w2[4];
    const float* b1[4]; const float* b2[4]; TOUT* out[4];
    const float* gate[4]; int ld[4];
};

template <int CIN, int COUT, int AIN, int AOUT, typename TOUT>
__global__ __launch_bounds__(256) void mgemmN_kernel(GA<TOUT> a, int nrows)
{
    __shared__ __align__(16) u16 Wt[128 * 136];
    const int y = blockIdx.y;
    const float* in = a.in[y];
    const u16* W1 = a.w1[y];
    const u16* W2 = a.w2[y];
    const float* b1 = a.b1[y];
    const float* b2 = a.b2[y];
    TOUT* out = a.out[y];
    const int ldout = a.ld[y];
    const bool split = (W2 != nullptr);

    const int tid = threadIdx.x;
    const int lane = tid & 63, wid = tid >> 6;
    const int rsub = lane & 15;
    const int kgrp = (lane >> 4) * 8;
    const int rowblk = blockIdx.x * 128;

    float g = 0.f;
    if (AOUT == 2) g = 1.0f / (1.0f + __expf(-a.gate[y][0]));

#pragma unroll
    for (int cc = 0; cc < COUT; cc += 128) {
        const u16* Ws = (split && cc) ? W2 : W1;
        const float* bs = (split && cc) ? b2 : b1;
        const int ldw  = split ? 128 : COUT;
        const int wcol = split ? 0 : cc;
        const int boff = split ? 0 : cc;

        f32x4 acc[2][8];
#pragma unroll
        for (int t2 = 0; t2 < 2; ++t2)
#pragma unroll
            for (int ct = 0; ct < 8; ++ct) acc[t2][ct] = (f32x4){0.f, 0.f, 0.f, 0.f};

#pragma unroll
        for (int kc = 0; kc < CIN; kc += 128) {
            __syncthreads();
            for (int i = tid; i < 128 * 32; i += 256) {
                int k = i >> 5, c4 = (i & 31) << 2;
                const uint2 w = *(const uint2*)&Ws[(size_t)(kc + k) * ldw + wcol + c4];
                Wt[(c4 + 0) * 136 + k] = (u16)(w.x & 0xffffu);
                Wt[(c4 + 1) * 136 + k] = (u16)(w.x >> 16);
                Wt[(c4 + 2) * 136 + k] = (u16)(w.y & 0xffffu);
                Wt[(c4 + 3) * 136 + k] = (u16)(w.y >> 16);
            }
            __syncthreads();
#pragma unroll
            for (int t2 = 0; t2 < 2; ++t2) {
                const int arow = rowblk + t2 * 64 + wid * 16 + rsub;
                const int asrc = (arow < nrows) ? arow : (nrows - 1);
                const float* ap0 = in + (size_t)asrc * CIN + kc;
#pragma unroll
                for (int ks = 0; ks < 4; ++ks) {
                    const int k0 = ks * 32 + kgrp;
                    const float4 a0 = *(const float4*)(ap0 + k0);
                    const float4 a1 = *(const float4*)(ap0 + k0 + 4);
                    float av[8] = {a0.x, a0.y, a0.z, a0.w, a1.x, a1.y, a1.z, a1.w};
                    short8v af;
#pragma unroll
                    for (int j = 0; j < 8; ++j) {
                        float xv = av[j];
                        if (AIN == 1) xv = gelu_f(xv);
                        af[j] = (short)f2bf(xv);
                    }
#pragma unroll
                    for (int ct = 0; ct < 8; ++ct) {
                        const short8v b =
                            *(const short8v*)&Wt[(ct * 16 + rsub) * 136 + k0];
                        acc[t2][ct] = __builtin_amdgcn_mfma_f32_16x16x32_bf16(
                            af, b, acc[t2][ct], 0, 0, 0);
                    }
                }
            }
        }
#pragma unroll
        for (int t2 = 0; t2 < 2; ++t2) {
            const int orow0 = rowblk + t2 * 64 + wid * 16 + (lane >> 4) * 4;
#pragma unroll
            for (int ct = 0; ct < 8; ++ct) {
                const int col = cc + ct * 16 + rsub;
                const float bv = bs[boff + ct * 16 + rsub];
#pragma unroll
                for (int r = 0; r < 4; ++r) {
                    const int orow = orow0 + r;
                    if (orow >= nrows) continue;
                    float v = acc[t2][ct][r] + bv;
                    if (AOUT == 1) v = fmaxf(v, 0.f);
                    size_t o = (size_t)orow * ldout + col;
                    if constexpr (sizeof(TOUT) == 2) {
                        ((u16*)out)[o] = f2bf(v);
                    } else {
                        float* of = (float*)out;
                        if (AOUT == 2) v = g * v + (1.0f - g) * of[o];
                        of[o] = v;
                    }
                }
            }
        }
    }
}

// ---------------- decoder GEMM (f32 W, direct A loads) ------------------------------
template <int CIN, int COUT, int AOUT>
__global__ __launch_bounds__(256) void dgemm_kernel(
    const float* __restrict__ in, const float* __restrict__ W,
    const float* __restrict__ bias, float* __restrict__ out, int nrows)
{
    __shared__ __align__(16) u16 Wt[128 * 136];
    const int tid = threadIdx.x;
    const int lane = tid & 63, wid = tid >> 6;
    const int rsub = lane & 15;
    const int kgrp = (lane >> 4) * 8;
    const int rowblk = blockIdx.x * 128;

#pragma unroll
    for (int cc = 0; cc < COUT; cc += 128) {
        f32x4 acc[2][8];
#pragma unroll
        for (int t2 = 0; t2 < 2; ++t2)
#pragma unroll
            for (int ct = 0; ct < 8; ++ct) acc[t2][ct] = (f32x4){0.f, 0.f, 0.f, 0.f};

#pragma unroll
        for (int kc = 0; kc < CIN; kc += 128) {
            __syncthreads();
            for (int i = tid; i < 128 * 32; i += 256) {
                int k = i >> 5, c4 = (i & 31) << 2;
                const float4 w = *(const float4*)&W[(size_t)(kc + k) * COUT + cc + c4];
                Wt[(c4 + 0) * 136 + k] = f2bf(w.x);
                Wt[(c4 + 1) * 136 + k] = f2bf(w.y);
                Wt[(c4 + 2) * 136 + k] = f2bf(w.z);
                Wt[(c4 + 3) * 136 + k] = f2bf(w.w);
            }
            __syncthreads();
#pragma unroll
            for (int t2 = 0; t2 < 2; ++t2) {
                const int arow = rowblk + t2 * 64 + wid * 16 + rsub;
                const int asrc = (arow < nrows) ? arow : (nrows - 1);
                const float* ap0 = in + (size_t)asrc * CIN + kc;
#pragma unroll
                for (int ks = 0; ks < 4; ++ks) {
                    const int k0 = ks * 32 + kgrp;
                    const float4 a0 = *(const float4*)(ap0 + k0);
                    const float4 a1 = *(const float4*)(ap0 + k0 + 4);
                    float av[8] = {a0.x, a0.y, a0.z, a0.w, a1.x, a1.y, a1.z, a1.w};
                    short8v af;
#pragma unroll
                    for (int j = 0; j < 8; ++j) af[j] = (short)f2bf(av[j]);
#pragma unroll
                    for (int ct = 0; ct < 8; ++ct) {
                        const short8v b =
                            *(const short8v*)&Wt[(ct * 16 + rsub) * 136 + k0];
                        acc[t2][ct] = __builtin_amdgcn_mfma_f32_16x16x32_bf16(
                            af, b, acc[t2][ct], 0, 0, 0);
                    }
                }
            }
        }
#pragma unroll
        for (int t2 = 0; t2 < 2; ++t2) {
            const int orow0 = rowblk + t2 * 64 + wid * 16 + (lane >> 4) * 4;
#pragma unroll
            for (int ct = 0; ct < 8; ++ct) {
                const int col = cc + ct * 16 + rsub;
                const float bv = bias[col];
#pragma unroll
                for (int r = 0; r < 4; ++r) {
                    const int orow = orow0 + r;
                    if (orow >= nrows) continue;
                    float v = acc[t2][ct][r] + bv;
                    if (AOUT == 1) v = fmaxf(v, 0.f);
                    out[(size_t)orow * COUT + col] = v;
                }
            }
        }
    }
}

// ---------------- convert 4 weight arrays to bf16 pool ------------------------------
__global__ void cvt4_kernel(const float* s0, const float* s1, const float* s2,
                            const float* s3, u16* __restrict__ pool, int n) {
    int y = blockIdx.y;
    const float* s = y == 0 ? s0 : y == 1 ? s1 : y == 2 ? s2 : s3;
    int i = blockIdx.x * 256 + threadIdx.x;
    if (i < n) pool[(size_t)y * n + i] = f2bf(s[i]);
}

// --- fuse arel into qW for ALL (l, dt, half): qWA_all[l*2+dt] [128][256] bf16 -------
__global__ __launch_bounds__(256) void fuse_all_kernel(
    const float* __restrict__ qW, const float* __restrict__ qb,
    const float* __restrict__ arel, u16* __restrict__ qWA_all,
    float* __restrict__ qbA_all)
{
    static const int etdt_[2][2] = {{1, 2}, {0, 3}};
    const int z = blockIdx.y;
    const int l = z >> 2, dt = (z >> 1) & 1, half = z & 1;
    const int et = etdt_[dt][half];
    const int rel = l * 4 + et, bd = l * 2 + dt;
    const float* qWl = qW + (size_t)bd * HID * HID;
    const float* qbl = qb + (size_t)bd * HID;
    const float* ar  = arel + (size_t)rel * 2048;
    u16* wout  = qWA_all + (size_t)bd * HID * 256;
    float* bout = qbA_all + (size_t)bd * 256;

    __shared__ float Al[2048];
    int tid = threadIdx.x;
    for (int i = tid; i < 2048; i += 256) Al[i] = ar[i];
    __syncthreads();
    int idx = blockIdx.x * 256 + tid;      // 64 x 256 = 16384
    int c = idx >> 7, col = idx & 127;
    int h = col >> 4, d = col & 15;
    const float* Ah = &Al[h * 256 + d * 16];
    const float* qr = &qWl[(size_t)c * 128 + h * 16];
    float acc = 0.f;
#pragma unroll
    for (int e = 0; e < 16; ++e) acc += qr[e] * Ah[e];
    wout[(size_t)c * 256 + half * 128 + col] = f2bf(acc);
    if (blockIdx.x == 0 && tid < 128) {
        int h2 = tid >> 4, d2 = tid & 15;
        const float* Ah2 = &Al[h2 * 256 + d2 * 16];
        const float* qb2 = &qbl[h2 * 16];
        float accb = 0.f;
#pragma unroll
        for (int e = 0; e < 16; ++e) accb += qb2[e] * Ah2[e];
        bout[half * 128 + tid] = accb;
    }
}

// ---------------- CSR-gather attention x2 edge types; 8-deep pipeline ---------------
__global__ __launch_bounds__(256) void gather2_kernel(
    const u32* __restrict__ qqA, const u32* __restrict__ qqB,
    const u32* __restrict__ kvA, const u32* __restrict__ kvB,
    const int* __restrict__ offA, const int* __restrict__ offB,
    const int* __restrict__ csrcA, const int* __restrict__ csrcB,
    const float* __restrict__ prelA, const float* __restrict__ prelB,
    const float* __restrict__ mrelA, const float* __restrict__ mrelB,
    float* __restrict__ aggA, float* __restrict__ aggB,
    int N, int accA, int accB)
{
    const int which = blockIdx.y;
    const u32* qq   = which ? qqB : qqA;
    const u32* kv   = which ? kvB : kvA;
    const int* off  = which ? offB : offA;
    const int* csrc = which ? csrcB : csrcA;
    const float* prel = which ? prelB : prelA;
    const float* mrel = which ? mrelB : mrelA;
    float* agg = which ? aggB : aggA;
    const int accum = which ? accB : accA;

    __shared__ float M[8 * 264];
    int tid = threadIdx.x;
    for (int i = tid; i < 2048; i += 256) M[(i >> 8) * 264 + (i & 255)] = mrel[i];
    __syncthreads();
    int lane = tid & 63, wid = tid >> 6;
    int h = lane >> 3, dp = lane & 7;
    int dst = blockIdx.x * 4 + wid;
    if (dst >= N) return;

    float prl = prel[h] * 0.25f;
    const u32 qu = qq[(size_t)dst * 128 + lane];
    const float qx = lo2f(qu), qy = hi2f(qu);
    const int beg = __builtin_amdgcn_readfirstlane(off[dst]);
    const int end = __builtin_amdgcn_readfirstlane(off[dst + 1]);
    float acc0 = 0.f, acc1 = 0.f, ssum = 0.f;

    u32 kA[4], vA[4], kB[4], vB[4];

    auto LOADG = [&](int g, u32* kk, u32* vv) {
#pragma unroll
        for (int i = 0; i < 4; ++i) {
            int e = g + i;
            int s = (e < end) ? csrc[e] : 0;
            const u32* base = kv + ((size_t)(u32)s << 7);
            kk[i] = base[lane];
            vv[i] = base[64 + lane];
        }
    };
    auto COMPG = [&](int g, const u32* kk, const u32* vv) {
#pragma unroll
        for (int i = 0; i < 4; ++i) {
            float p = qx * lo2f(kk[i]) + qy * hi2f(kk[i]);
            p += __shfl_xor(p, 1);
            p += __shfl_xor(p, 2);
            p += __shfl_xor(p, 4);
            float sarg = fminf(fmaxf(p * prl, -60.f), 60.f);
            float ex = (g + i < end) ? __expf(sarg) : 0.f;
            ssum += ex;
            acc0 += ex * lo2f(vv[i]);
            acc1 += ex * hi2f(vv[i]);
        }
    };

    if (beg < end) {
        LOADG(beg, kA, vA);
        LOADG(beg + 4, kB, vB);
        int g = beg;
        for (;;) {
            COMPG(g, kA, vA);
            if (g + 8 < end) LOADG(g + 8, kA, vA);
            g += 4;
            if (g >= end) break;
            COMPG(g, kB, vB);
            if (g + 8 < end) LOADG(g + 8, kB, vB);
            g += 4;
            if (g >= end) break;
        }
    }

    float inv = 1.0f / (ssum + 1e-16f);
    acc0 *= inv; acc1 *= inv;

    float o0 = 0.f, o1 = 0.f;
    const float* Mh = &M[h * 264];
#pragma unroll
    for (int dd = 0; dd < 8; ++dd) {
        float b0 = __shfl(acc0, (h << 3) | dd);
        float b1 = __shfl(acc1, (h << 3) | dd);
        const float2 m0 = *(const float2*)&Mh[(2 * dd) * 16 + dp * 2];
        const float2 m1 = *(const float2*)&Mh[(2 * dd + 1) * 16 + dp * 2];
        o0 += b0 * m0.x + b1 * m1.x;
        o1 += b0 * m0.y + b1 * m1.y;
    }
    float* ap = &agg[(size_t)dst * 128 + lane * 2];
    if (accum) { ap[0] += o0; ap[1] += o1; }
    else       { ap[0] = o0;  ap[1] = o1;  }
}

// ---------------- CSR build (4 edge types per dispatch via blockIdx.y) --------------
__global__ void hist4_kernel(const int* e0, const int* e1, const int* e2,
                             const int* e3, int* __restrict__ deg, int E, int N) {
    int et = blockIdx.y;
    const int* ei = et == 0 ? e0 : et == 1 ? e1 : et == 2 ? e2 : e3;
    int i = blockIdx.x * 256 + threadIdx.x;
    if (i < E) atomicAdd(&deg[et * N + ei[E + i]], 1);
}
__global__ __launch_bounds__(256) void scan_part4(const int* __restrict__ deg,
                                                  int* __restrict__ bsum, int N) {
    int et = blockIdx.y, b = blockIdx.x, tid = threadIdx.x;
    deg += (size_t)et * N;
    int base = b * 1024 + tid * 4;
    int s = 0;
#pragma unroll
    for (int i = 0; i < 4; ++i) { int idx = base + i; if (idx < N) s += deg[idx]; }
    __shared__ int sm[256];
    sm[tid] = s; __syncthreads();
    for (int d = 128; d > 0; d >>= 1) {
        if (tid < d) sm[tid] += sm[tid + d];
        __syncthreads();
    }
    if (tid == 0) bsum[et * 64 + b] = sm[0];
}
__global__ __launch_bounds__(256) void scan_top4(int* __restrict__ bsum,
                                                 int* __restrict__ offs,
                                                 int NB, int N) {
    int et = blockIdx.x, tid = threadIdx.x;
    bsum += et * 64;
    int* off = offs + (size_t)et * (N + 1);
    __shared__ int sm[256];
    int v = (tid < NB) ? bsum[tid] : 0;
    sm[tid] = v; __syncthreads();
    for (int d = 1; d < 256; d <<= 1) {
        int t = (tid >= d) ? sm[tid - d] : 0;
        __syncthreads();
        sm[tid] += t;
        __syncthreads();
    }
    if (tid < NB) bsum[tid] = sm[tid] - v;
    if (tid == 255) off[N] = sm[255];
}
__global__ __launch_bounds__(256) void scan_fin4(const int* __restrict__ deg,
                                                 const int* __restrict__ bsum,
                                                 int* __restrict__ offs, int N) {
    int et = blockIdx.y, b = blockIdx.x, tid = threadIdx.x;
    deg += (size_t)et * N;
    bsum += et * 64;
    int* off = offs + (size_t)et * (N + 1);
    int base = b * 1024 + tid * 4;
    int v[4]; int s = 0;
#pragma unroll
    for (int i = 0; i < 4; ++i) {
        int idx = base + i;
        v[i] = (idx < N) ? deg[idx] : 0;
        s += v[i];
    }
    __shared__ int sm[256];
    sm[tid] = s; __syncthreads();
    for (int d = 1; d < 256; d <<= 1) {
        int t = (tid >= d) ? sm[tid - d] : 0;
        __syncthreads();
        sm[tid] += t;
        __syncthreads();
    }
    int run = bsum[b] + sm[tid] - s;
#pragma unroll
    for (int i = 0; i < 4; ++i) {
        int idx = base + i;
        if (idx < N) { off[idx] = run; run += v[i]; }
    }
}
__global__ void scatter4_kernel(const int* e0, const int* e1, const int* e2,
                                const int* e3, const int* __restrict__ offs,
                                int* __restrict__ cnt, int* __restrict__ csrcs,
                                int E, int N) {
    int et = blockIdx.y;
    const int* ei = et == 0 ? e0 : et == 1 ? e1 : et == 2 ? e2 : e3;
    int i = blockIdx.x * 256 + threadIdx.x;
    if (i < E) {
        int d = ei[E + i];
        int pos = offs[(size_t)et * (N + 1) + d] + atomicAdd(&cnt[et * N + d], 1);
        csrcs[(size_t)et * E + pos] = ei[i];
    }
}

// ---------------- L2 normalize: one wave per row, f32 -> f32 ------------------------
__global__ __launch_bounds__(256) void nnorm(
    const float* __restrict__ h0, float* __restrict__ emb, int N)
{
    int lane = threadIdx.x & 63, wid = threadIdx.x >> 6;
    int n = blockIdx.x * 4 + wid;
    if (n >= N) return;
    const float2 v = *(const float2*)&h0[(size_t)n * 128 + lane * 2];
    float s = v.x * v.x + v.y * v.y;
#pragma unroll
    for (int m = 1; m < 64; m <<= 1) s += __shfl_xor(s, m);
    float sc = 1.0f / fmaxf(sqrtf(s), 1e-12f);
    if (!isfinite(sc)) sc = 0.f;
    float2* op = (float2*)&emb[(size_t)n * 128 + lane * 2];
    *op = make_float2(v.x * sc, v.y * sc);
}

// ---------------- sentinel (f32) ----------------------------------------------------
__global__ void sentinel_kernel(float* out, int n, float val) {
    int i = blockIdx.x * 256 + threadIdx.x;
    if (i < n) out[i] = val;
}

extern "C" void kernel_launch(void* const* d_in, const int* in_sizes, int n_in,
                              void* d_out, int out_size, void* d_ws, size_t ws_size,
                              hipStream_t stream)
{
    const int N = in_sizes[0] / (TTYPES * INC);
    const int E = in_sizes[19] / 2;
    const size_t NH = (size_t)N * HID;

    const size_t need = 6 * NH * 4;   // 153.6 MB (proven available)
    if (ws_size < need) {
        sentinel_kernel<<<(out_size + 255) / 256, 256, 0, stream>>>(
            (float*)d_out, out_size, 30.0f);
        return;
    }

    const float* x     = (const float*)d_in[0];
    const float* encW  = (const float*)d_in[1];
    const float* encb  = (const float*)d_in[2];
    const float* kW    = (const float*)d_in[3];
    const float* kb_   = (const float*)d_in[4];
    const float* qW    = (const float*)d_in[5];
    const float* qb    = (const float*)d_in[6];
    const float* vW    = (const float*)d_in[7];
    const float* vb_   = (const float*)d_in[8];
    const float* aW    = (const float*)d_in[9];
    const float* ab    = (const float*)d_in[10];
    const float* skipw = (const float*)d_in[11];
    const float* arel  = (const float*)d_in[12];
    const float* mrel  = (const float*)d_in[13];
    const float* prel  = (const float*)d_in[14];
    const float* dW1   = (const float*)d_in[15];
    const float* db1   = (const float*)d_in[16];
    const float* dW2   = (const float*)d_in[17];
    const float* db2   = (const float*)d_in[18];

    float* hbuf = (float*)d_ws;
    float* agg0 = hbuf + 2 * NH;
    u32* kv0    = (u32*)(agg0 + NH);      // [N][128] k|v packed bf16, src type 0
    u32* kv1    = kv0 + NH;               // src type 1
    u32* qq2_0  = kv1 + NH;               // [N][128] qq halves, dt=0

    // ---- d_out scratch ----
    float* agg1 = (float*)d_out;                 // emb region, dead before nnorm
    int*   ip   = (int*)((float*)d_out + NH);    // rec region
    int* deg   = ip;  ip += 4 * N;
    int* cnt   = ip;  ip += 4 * N;
    int* offs  = ip;  ip += 4 * (N + 1);
    int* csrcs = ip;  ip += 4 * E;
    u16* qWA_all = (u16*)ip;                     // [4][128][256] bf16
    float* qbA_all = (float*)(qWA_all + 4 * HID * 256);
    int* bsum   = (int*)(qbA_all + 4 * 256);     // [4][64]
    u16* wpool  = (u16*)(bsum + 256);            // 4 x 65536 bf16 weights
    const int WN = 65536;
    u16* encB = wpool;
    u16* kB   = wpool + WN;
    u16* vB   = wpool + 2 * WN;
    u16* aB   = wpool + 3 * WN;
    u32* qq2_1 = (u32*)(wpool + 4 * WN);         // [N][128] qq halves, dt=1
    u32* qq2[2] = {qq2_0, qq2_1};
    float* aggs[2] = {agg0, agg1};

    const int egrid = (E + 255) / 256;
    const int RB    = (N + 127) / 128;
    const int GW    = (N + 3) / 4;
    const int NB1   = (N + 1023) >> 10;

    const int* e0 = (const int*)d_in[19];
    const int* e1 = (const int*)d_in[20];
    const int* e2 = (const int*)d_in[21];
    const int* e3 = (const int*)d_in[22];

    // ---- prep: weight pool + all arel folds + CSR build ----
    cvt4_kernel<<<dim3(WN / 256, 4), 256, 0, stream>>>(encW, kW, vW, aW, wpool, WN);
    fuse_all_kernel<<<dim3(64, 8), 256, 0, stream>>>(qW, qb, arel, qWA_all, qbA_all);
    hipMemsetAsync(deg, 0, (size_t)8 * N * 4, stream);
    hist4_kernel<<<dim3(egrid, 4), 256, 0, stream>>>(e0, e1, e2, e3, deg, E, N);
    scan_part4<<<dim3(NB1, 4), 256, 0, stream>>>(deg, bsum, N);
    scan_top4<<<4, 256, 0, stream>>>(bsum, offs, NB1, N);
    scan_fin4<<<dim3(NB1, 4), 256, 0, stream>>>(deg, bsum, offs, N);
    scatter4_kernel<<<dim3(egrid, 4), 256, 0, stream>>>(e0, e1, e2, e3, offs, cnt,
                                                        csrcs, E, N);

    // ---- encoder: both node types in one dispatch ----
    {
        GA<float> ga{};
        for (int t = 0; t < 2; ++t) {
            ga.in[t] = x + (size_t)t * N * INC;
            ga.w1[t] = encB + (size_t)t * INC * HID;
            ga.w2[t] = nullptr;
            ga.b1[t] = encb + t * HID;
            ga.out[t] = hbuf + t * NH;
            ga.ld[t] = HID;
        }
        mgemmN_kernel<INC, HID, 0, 1, float><<<dim3(RB, 2), 256, 0, stream>>>(ga, N);
    }

    for (int l = 0; l < 2; ++l) {
        // proj4: qq_dt0, qq_dt1, kv_st0, kv_st1 (all read pre-update h)
        {
            GA<u16> ga{};
            for (int dt = 0; dt < 2; ++dt) {
                int bd = l * 2 + dt;
                ga.in[dt] = hbuf + dt * NH;
                ga.w1[dt] = qWA_all + (size_t)bd * HID * 256;
                ga.w2[dt] = nullptr;
                ga.b1[dt] = qbA_all + (size_t)bd * 256;
                ga.out[dt] = (u16*)qq2[dt];
                ga.ld[dt] = 256;
            }
            u32* kvs[2] = {kv0, kv1};
            for (int st = 0; st < 2; ++st) {
                int bs = l * 2 + st, y = 2 + st;
                ga.in[y] = hbuf + st * NH;
                ga.w1[y] = kB + (size_t)bs * HID * HID;
                ga.w2[y] = vB + (size_t)bs * HID * HID;
                ga.b1[y] = kb_ + (size_t)bs * HID;
                ga.b2[y] = vb_ + (size_t)bs * HID;
                ga.out[y] = (u16*)kvs[st];
                ga.ld[y] = 256;
            }
            mgemmN_kernel<HID, 256, 0, 0, u16><<<dim3(RB, 4), 256, 0, stream>>>(ga, N);
        }
        // gathers: A = {et0 (dt1,st0) init agg1, et1 (dt0,st1) init agg0}
        //          B = {et2 (dt0,st0) acc agg0, et3 (dt1,st1) acc agg1}
        gather2_kernel<<<dim3(GW, 2), 256, 0, stream>>>(
            qq2_1, qq2_0, kv0, kv1,
            offs + 0 * (N + 1), offs + 1 * (size_t)(N + 1),
            csrcs + 0 * (size_t)E, csrcs + 1 * (size_t)E,
            prel + (size_t)(l * 4 + 0) * HH, prel + (size_t)(l * 4 + 1) * HH,
            mrel + (size_t)(l * 4 + 0) * 2048, mrel + (size_t)(l * 4 + 1) * 2048,
            agg1, agg0, N, 0, 0);
        gather2_kernel<<<dim3(GW, 2), 256, 0, stream>>>(
            qq2_0 + 64, qq2_1 + 64, kv0, kv1,
            offs + 2 * (size_t)(N + 1), offs + 3 * (size_t)(N + 1),
            csrcs + 2 * (size_t)E, csrcs + 3 * (size_t)E,
            prel + (size_t)(l * 4 + 2) * HH, prel + (size_t)(l * 4 + 3) * HH,
            mrel + (size_t)(l * 4 + 2) * 2048, mrel + (size_t)(l * 4 + 3) * 2048,
            agg0, agg1, N, 1, 1);
        // a2: h[t] = g*(gelu(agg[t]) @ aW + ab) + (1-g)*h[t]
        {
            GA<float> ga{};
            for (int t = 0; t < 2; ++t) {
                int b = l * 2 + t;
                ga.in[t] = aggs[t];
                ga.w1[t] = aB + (size_t)b * HID * HID;
                ga.w2[t] = nullptr;
                ga.b1[t] = ab + (size_t)b * HID;
                ga.out[t] = hbuf + t * NH;
                ga.gate[t] = skipw + b;
                ga.ld[t] = HID;
            }
            mgemmN_kernel<HID, HID, 1, 2, float><<<dim3(RB, 2), 256, 0, stream>>>(ga, N);
        }
    }

    float* emb = (float*)d_out;           // [N][128] f32
    float* rec = emb + NH;                // [N][256] f32
    nnorm<<<GW, 256, 0, stream>>>(hbuf, emb, N);
    dgemm_kernel<HID, HID, 1><<<RB, 256, 0, stream>>>(hbuf, dW1, db1, agg0, N);
    dgemm_kernel<HID, 256, 0><<<RB, 256, 0, stream>>>(agg0, dW2, db2, rec, N);
}